// Round 4
// baseline (12261.138 us; speedup 1.0000x reference)
//
#include <hip/hip_runtime.h>

// LSTM_15556371546645 — MI355X (gfx950), round 10
// R9: placement-VERIFIED XCD-local exchange.
//  - 32 blocks; each reads its real XCC_ID (s_getreg hwreg 20, HW-verified on
//    MI355X) and all 32 rendezvous once per dispatch. Roles are assigned by
//    rank over (xcc,bid): groups of 4 are formed from blocks measured to
//    share an XCD whenever placement allows (round-robin / linear / packed
//    all co-locate). Ranks 16..31 exit.
//  - fast groups (4 ids equal): publish = plain store (shared XCD L2) and
//    poll = sc0 rounds (~300cy RT) with every-4th agent safety round.
//    non-fast groups: exact R8 agent protocol.
//  - producers ALWAYS dual-store (plain + sc1/MALL): mis-detection can cost
//    speed, never correctness or liveness.
//  - L1 fast path: both gathers (h1 stale + h0 fresh) before ONE barrier.
//  - xg0: one-step software prefetch (issued post-gather, used next step) so
//    poll vmcnt(0) rounds never absorb xg HBM latency.
// R7 post-mortem: its 2.1x regression is the exact signature of FAILED
// co-location (stale clean sentinel line in reader L2 can never be
// invalidated by a remote XCD store) — hence runtime verification here.

typedef unsigned short u16;
typedef unsigned long long u64;
typedef __attribute__((ext_vector_type(8))) short short8;   // 8 x bf16
typedef __attribute__((ext_vector_type(4))) float f32x4;    // MFMA acc

#define SEQ  2048
#define CS   128            // chunk steps
#define NCH  (SEQ / CS)     // 16 chunks
#define CN   (CS * 64)      // rows per chunk = 8192
#define SLOT 16384          // u16 per h slot (64 b x 256 j)
#define HXBYTES ((size_t)(CS + 1) * SLOT * 2)   // 4,227,072 B per layer
#define SENT64 0x7F7F7F7F7F7F7F7FULL

// ---------------- numeric helpers ----------------
__device__ __forceinline__ u16 f2bf(float f) {
  unsigned u = __float_as_uint(f);
  unsigned r = u + 0x7fffu + ((u >> 16) & 1u);   // RTNE
  return (u16)(r >> 16);
}
__device__ __forceinline__ float bf2f(u16 h) {
  return __uint_as_float(((unsigned)h) << 16);
}
__device__ __forceinline__ float sigf(float x) {
  return __builtin_amdgcn_rcpf(1.f + __expf(-x));
}
__device__ __forceinline__ float tanhf_fast(float x) {
  return 1.f - 2.f * __builtin_amdgcn_rcpf(1.f + __expf(2.f * x));
}

__device__ __forceinline__ u64 aload(const u16* p) {
  return __hip_atomic_load((const u64*)p, __ATOMIC_RELAXED, __HIP_MEMORY_SCOPE_AGENT);
}
__device__ __forceinline__ void astore(u16* p, u64 v) {
  __hip_atomic_store((u64*)p, v, __ATOMIC_RELAXED, __HIP_MEMORY_SCOPE_AGENT);
}
// plain store (L2 fast path); kept in asm so it is never folded away
__device__ __forceinline__ void st_plain(u16* p, u64 v) {
  asm volatile("global_store_dwordx2 %0, %1, off" :: "v"(p), "v"(v));
}

// 8 x 8B agent-coherent loads (sc0 sc1 -> MALL), rows stride 2048B, NO wait.
__device__ __forceinline__ void ld8_issue(const u16* a0, u64 v[8]) {
  asm volatile(
      "global_load_dwordx2 %0, %8, off sc0 sc1\n\t"
      "global_load_dwordx2 %1, %8, off offset:2048 sc0 sc1\n\t"
      "global_load_dwordx2 %2, %9, off sc0 sc1\n\t"
      "global_load_dwordx2 %3, %9, off offset:2048 sc0 sc1\n\t"
      "global_load_dwordx2 %4, %10, off sc0 sc1\n\t"
      "global_load_dwordx2 %5, %10, off offset:2048 sc0 sc1\n\t"
      "global_load_dwordx2 %6, %11, off sc0 sc1\n\t"
      "global_load_dwordx2 %7, %11, off offset:2048 sc0 sc1"
      : "=&v"(v[0]), "=&v"(v[1]), "=&v"(v[2]), "=&v"(v[3]),
        "=&v"(v[4]), "=&v"(v[5]), "=&v"(v[6]), "=&v"(v[7])
      : "v"(a0), "v"(a0 + 2048), "v"(a0 + 4096), "v"(a0 + 6144)
      : "memory");
}
__device__ __forceinline__ void vmwait8(u64 v[8]) {
  asm volatile("s_waitcnt vmcnt(0)"
      : "+v"(v[0]), "+v"(v[1]), "+v"(v[2]), "+v"(v[3]),
        "+v"(v[4]), "+v"(v[5]), "+v"(v[6]), "+v"(v[7]) :: "memory");
}
__device__ __forceinline__ void ld8_agent(const u16* a0, u64 v[8]) {
  ld8_issue(a0, v);
  vmwait8(v);
}
// 8 x 8B sc0-only loads (L1-bypass, served by the SHARED per-XCD L2) + wait.
__device__ __forceinline__ void ld8_sc0(const u16* a0, u64 v[8]) {
  asm volatile(
      "global_load_dwordx2 %0, %8, off sc0\n\t"
      "global_load_dwordx2 %1, %8, off offset:2048 sc0\n\t"
      "global_load_dwordx2 %2, %9, off sc0\n\t"
      "global_load_dwordx2 %3, %9, off offset:2048 sc0\n\t"
      "global_load_dwordx2 %4, %10, off sc0\n\t"
      "global_load_dwordx2 %5, %10, off offset:2048 sc0\n\t"
      "global_load_dwordx2 %6, %11, off sc0\n\t"
      "global_load_dwordx2 %7, %11, off offset:2048 sc0\n\t"
      "s_waitcnt vmcnt(0)"
      : "=&v"(v[0]), "=&v"(v[1]), "=&v"(v[2]), "=&v"(v[3]),
        "=&v"(v[4]), "=&v"(v[5]), "=&v"(v[6]), "=&v"(v[7])
      : "v"(a0), "v"(a0 + 2048), "v"(a0 + 4096), "v"(a0 + 6144)
      : "memory");
}

__device__ __forceinline__ void wg_barrier() {
  __builtin_amdgcn_sched_barrier(0);
  asm volatile("s_waitcnt lgkmcnt(0)" ::: "memory");
  __builtin_amdgcn_s_barrier();
  __builtin_amdgcn_sched_barrier(0);
}

// Row permutation: row' = p*256 + T*16 + u (T=0..15,u=0..15)
// gate g=u&3; j=(T>>2)*16+((u>>2)<<2)+(T&3); r_orig=g*256+p*64+j  [HW-verified R3]
__device__ __forceinline__ int rowp_to_orig(int rowp) {
  int p = rowp >> 8, T = (rowp >> 4) & 15, u = rowp & 15;
  int g = u & 3;
  int j = ((T >> 2) << 4) + ((u >> 2) << 2) + (T & 3);
  return g * 256 + p * 64 + j;
}

// ---------------- prep ----------------
#define PREP_TOTAL (16384 + 65536 + 1024 + 1024 + 524288 + 262144 + 32768 + 64)

__global__ void prep_kernel(const float* __restrict__ enc_w, const float* __restrict__ enc_b,
                            const float* __restrict__ w_ih, const float* __restrict__ w_hh,
                            const float* __restrict__ b_ih, const float* __restrict__ b_hh,
                            const float* __restrict__ dec_w,
                            u16* __restrict__ WDEC, u16* __restrict__ CW,
                            float* __restrict__ CB, float* __restrict__ B1P,
                            u16* __restrict__ WHHP, u16* __restrict__ WIH1P,
                            u16* __restrict__ HX0, u16* __restrict__ HX1,
                            int* __restrict__ RDV)
{
  size_t idx = (size_t)blockIdx.x * 256 + threadIdx.x;
  if (idx < 16384) { WDEC[idx] = f2bf(dec_w[idx]); return; }
  idx -= 16384;
  if (idx < 65536) {
    int rowp = (int)(idx >> 6), f = (int)(idx & 63);
    int r = rowp_to_orig(rowp);
    float a = 0.f;
    for (int k = 0; k < 256; ++k) a += w_ih[r * 256 + k] * enc_w[k * 64 + f];
    CW[idx] = f2bf(a);
    return;
  }
  idx -= 65536;
  if (idx < 1024) {
    int r = rowp_to_orig((int)idx);
    float a = b_ih[r] + b_hh[r];
    for (int k = 0; k < 256; ++k) a += w_ih[r * 256 + k] * enc_b[k];
    CB[idx] = a;
    return;
  }
  idx -= 1024;
  if (idx < 1024) {
    int r = rowp_to_orig((int)idx);
    B1P[idx] = b_ih[1024 + r] + b_hh[1024 + r];
    return;
  }
  idx -= 1024;
  if (idx < 524288) {   // WHHP: flat = ((((l*4+p)*4+w)*4+t)*8+kc)*512 + lane*8 + e
    int l = (int)(idx >> 18);
    int rem = (int)(idx & 262143);
    int e = rem & 7, lane = (rem >> 3) & 63, kc = (rem >> 9) & 7;
    int t = (rem >> 12) & 3, wv = (rem >> 14) & 3, pp = (rem >> 16) & 3;
    int u = lane & 15, qd = lane >> 4;
    int g = u & 3;
    int j = wv * 16 + ((u >> 2) << 2) + t;
    int r = g * 256 + pp * 64 + j;
    int k = kc * 32 + qd * 8 + e;
    WHHP[idx] = f2bf(w_hh[(size_t)l * 262144 + (size_t)r * 256 + k]);
    return;
  }
  idx -= 524288;
  if (idx < 262144) {   // WIH1P (l=1)
    int rem = (int)idx;
    int e = rem & 7, lane = (rem >> 3) & 63, kc = (rem >> 9) & 7;
    int t = (rem >> 12) & 3, wv = (rem >> 14) & 3, pp = (rem >> 16) & 3;
    int u = lane & 15, qd = lane >> 4;
    int g = u & 3;
    int j = wv * 16 + ((u >> 2) << 2) + t;
    int r = g * 256 + pp * 64 + j;
    int k = kc * 32 + qd * 8 + e;
    WIH1P[idx] = f2bf(w_ih[262144 + (size_t)r * 256 + k]);
    return;
  }
  idx -= 262144;
  if (idx < 32768) {    // zero slot0 (overwrites the 0x7F memset)
    if (idx < 16384) HX0[idx] = 0;
    else             HX1[idx - 16384] = 0;
    return;
  }
  idx -= 32768;
  if (idx < 64) RDV[idx] = 0;
}

// ---------------- generic bf16 GEMM:  C(MxN) = A(MxK) * B(NxK)^T + bias ----------------
template<int KTILES, int OUTBF, int BMODE, int AF32>
__global__ __launch_bounds__(256, 1) void gemm_bt(
    const void* __restrict__ Av, const u16* __restrict__ B, void* __restrict__ Cv,
    const float* __restrict__ bias, size_t ldc)
{
  constexpr int K = KTILES * 64;
  __shared__ __align__(16) u16 Asl[64 * 72];
  __shared__ __align__(16) u16 Bsl[64 * 72];
  const int tid = threadIdx.x;
  const int w = tid >> 6, lane = tid & 63, lm = lane & 15, quad = lane >> 4;
  const size_t m0 = (size_t)blockIdx.y * 64, n0 = (size_t)blockIdx.x * 64;

  f32x4 acc[4];
#pragma unroll
  for (int nt = 0; nt < 4; ++nt) { f32x4 z = {0.f, 0.f, 0.f, 0.f}; acc[nt] = z; }

  for (int kb = 0; kb < KTILES; ++kb) {
    if (AF32) {
      const float* Af = (const float*)Av;
#pragma unroll
      for (int c = 0; c < 4; ++c) {
        int idx = c * 256 + tid;
        int row = idx >> 4, k4 = idx & 15;
        float4 v = *(const float4*)(Af + (m0 + row) * (size_t)K + kb * 64 + k4 * 4);
        u64 pv = (u64)f2bf(v.x) | ((u64)f2bf(v.y) << 16) |
                 ((u64)f2bf(v.z) << 32) | ((u64)f2bf(v.w) << 48);
        *(u64*)(&Asl[row * 72 + k4 * 4]) = pv;
      }
    } else {
      const u16* Ab = (const u16*)Av;
#pragma unroll
      for (int c = 0; c < 2; ++c) {
        int idx = c * 256 + tid;
        int row = idx >> 3, k8 = idx & 7;
        *(uint4*)(&Asl[row * 72 + k8 * 8]) =
            *(const uint4*)(Ab + (m0 + row) * (size_t)K + kb * 64 + k8 * 8);
      }
    }
#pragma unroll
    for (int c = 0; c < 2; ++c) {
      int idx = c * 256 + tid;
      int row = idx >> 3, k8 = idx & 7;
      *(uint4*)(&Bsl[row * 72 + k8 * 8]) =
          *(const uint4*)(B + (n0 + row) * (size_t)K + kb * 64 + k8 * 8);
    }
    __syncthreads();
#pragma unroll
    for (int kc = 0; kc < 2; ++kc) {
      short8 a = *(const short8*)(&Asl[(w * 16 + lm) * 72 + kc * 32 + quad * 8]);
#pragma unroll
      for (int nt = 0; nt < 4; ++nt) {
        short8 b = *(const short8*)(&Bsl[(nt * 16 + lm) * 72 + kc * 32 + quad * 8]);
        acc[nt] = __builtin_amdgcn_mfma_f32_16x16x32_bf16(a, b, acc[nt], 0, 0, 0);
      }
    }
    __syncthreads();
  }
#pragma unroll
  for (int nt = 0; nt < 4; ++nt) {
    size_t n = n0 + nt * 16 + lm;
    float bn = (BMODE == 1) ? bias[n] : 0.f;
#pragma unroll
    for (int r = 0; r < 4; ++r) {
      size_t m = m0 + w * 16 + quad * 4 + r;
      float v = acc[nt][r] + ((BMODE == 2) ? bias[m] : bn);
      if (OUTBF) ((u16*)Cv)[m * ldc + n] = f2bf(v);
      else       ((float*)Cv)[m * ldc + n] = v;
    }
  }
}

// ---------------- sentinel-poll gather: one 32 b x 256 j h-slab -> LDS ----------------
// fastmode: sc0 rounds (shared-XCD L2) with every-4th agent safety round.
__device__ __forceinline__ void gather32(const u16* __restrict__ src,
                                         u16* __restrict__ dst,
                                         int tid, int n2, bool skip, int p,
                                         bool fastmode)
{
  const int j4 = tid & 63;
  const int tw = tid >> 6;
  if (skip && ((j4 >> 4) == p)) return;
  const u16* a0 = src + ((size_t)(n2 * 32 + tw) * 256 + j4 * 4);
  u64 v[8];
  if (fastmode) ld8_sc0(a0, v); else ld8_agent(a0, v);
  for (int r = 1;; ++r) {
    bool bad = false;
#pragma unroll
    for (int i = 0; i < 8; ++i) bad |= (v[i] == SENT64);
    if (!bad) break;
    if (fastmode && (r & 3)) ld8_sc0(a0, v); else ld8_agent(a0, v);
  }
#pragma unroll
  for (int i = 0; i < 8; ++i)
    *(u64*)(dst + (i * 4 + tw) * 264 + j4 * 4) = v[i];
}

// ---------------- fused 2-layer dataflow recurrence (32 blocks, 16 roles) ----------------
// Rendezvous assigns role = rank over (xcc,bid); ranks>=16 exit.
// role: p = role&3, layer = (role>>2)&1, n2 = role>>3.
__global__ __launch_bounds__(256, 1) void lstm_fused(
    const u16* __restrict__ xg0, u16* __restrict__ x2,
    const u16* __restrict__ whhp, const u16* __restrict__ wih1p,
    const float* __restrict__ b1p,
    u16* __restrict__ hx0, u16* __restrict__ hx1,
    float* __restrict__ cstb, int* __restrict__ RDV, int base)
{
  __shared__ __align__(16) u16 Hl[2][2][32 * 264];   // [parity][buf] +8 u16 row pad
  __shared__ int sh_role, sh_pf, sh_h0f;
  const int tid = threadIdx.x;
  const int bid = blockIdx.x;

  // ---- rendezvous: publish real XCC_ID, rank (xcc,bid), detect co-location ----
  {
    int myxcc = __builtin_amdgcn_s_getreg(6164) & 7;   // hwreg(20,0,4) = XCC_ID
    if (tid == 0) {
      __hip_atomic_store(&RDV[bid], myxcc, __ATOMIC_RELAXED, __HIP_MEMORY_SCOPE_AGENT);
      __hip_atomic_fetch_add(&RDV[32], 1, __ATOMIC_RELEASE, __HIP_MEMORY_SCOPE_AGENT);
      const int tgt = 32 * (base / CS + 1);
      while (__hip_atomic_load(&RDV[32], __ATOMIC_ACQUIRE, __HIP_MEMORY_SCOPE_AGENT) < tgt) {}
    }
    __syncthreads();
    if (tid < 64) {
      int id  = (tid < 32) ? (__hip_atomic_load(&RDV[tid], __ATOMIC_RELAXED,
                                                __HIP_MEMORY_SCOPE_AGENT) & 7) : 7;
      int key = (tid < 32) ? ((id << 8) | tid) : 0x7FFFFFFF;
      int rank = 0;
#pragma unroll
      for (int j = 0; j < 32; ++j) {
        int kj = __shfl(key, j);
        rank += (kj < key) ? 1 : 0;
      }
      int myrank = __shfl(rank, bid);
      int myid   = __shfl(id, bid);
      int g  = myrank >> 2;                 // my group
      int sg = (myrank >> 3) << 1;          // layer-0 group of my batch half
      u64 bg  = __ballot(tid < 32 && (rank >> 2) == g);
      u64 bgm = __ballot(tid < 32 && (rank >> 2) == g  && id == myid);
      u64 bs  = __ballot(tid < 32 && (rank >> 2) == sg);
      u64 bsm = __ballot(tid < 32 && (rank >> 2) == sg && id == myid);
      if (tid == 0) {
        sh_role = (myrank < 16) ? myrank : -1;
        sh_pf   = (bg == bgm) ? 1 : 0;
        sh_h0f  = (bs == bsm) ? 1 : 0;
      }
    }
    __syncthreads();
  }
  const int role = sh_role;
  if (role < 0) return;
  const bool fast   = sh_pf != 0;
  const bool h0fast = sh_h0f != 0;
  const int p = role & 3, layer = (role >> 2) & 1, n2 = role >> 3;
  const int lane = tid & 63, w = tid >> 6, lm = lane & 15, quad = lane >> 4;
  const int j4 = tid & 63, tw = tid >> 6;

  // ---- weights into VGPR fragments ----
  short8 wfh[4][8], wfi[4][8];
  {
    const u16* wp = whhp + (size_t)((layer * 4 + p) * 4 + w) * 16384 + lane * 8;
#pragma unroll
    for (int t = 0; t < 4; ++t)
#pragma unroll
      for (int kc = 0; kc < 8; ++kc)
        wfh[t][kc] = *(const short8*)(wp + (t * 8 + kc) * 512);
  }
  f32x4 bias_f[4];
  if (layer) {
    const u16* wp = wih1p + (size_t)(p * 4 + w) * 16384 + lane * 8;
#pragma unroll
    for (int t = 0; t < 4; ++t)
#pragma unroll
      for (int kc = 0; kc < 8; ++kc)
        wfi[t][kc] = *(const short8*)(wp + (t * 8 + kc) * 512);
#pragma unroll
    for (int t = 0; t < 4; ++t)
      bias_f[t] = *(const f32x4*)(b1p + p * 256 + (w * 4 + t) * 16 + quad * 4);
  }

  float* cp = cstb + (size_t)(((layer * 4 + p) * 2 + n2) * 256 + tid) * 8;
  float cst[4][2];
  if (base) {
#pragma unroll
    for (int t = 0; t < 4; ++t) { cst[t][0] = cp[t * 2]; cst[t][1] = cp[t * 2 + 1]; }
  } else {
#pragma unroll
    for (int t = 0; t < 4; ++t) { cst[t][0] = 0.f; cst[t][1] = 0.f; }
  }

  const int jcol = p * 64 + w * 16 + quad * 4;
  u16* myhx = layer ? hx1 : hx0;
  u64 hprev[2] = {0, 0};

  // xg prefetch (layer 0): xva = step s data, xvb = step s+1 (loaded mid-step)
  u64 xva[4][2], xvb[4][2];
  if (layer == 0) {
#pragma unroll
    for (int t = 0; t < 4; ++t)
#pragma unroll
      for (int nt = 0; nt < 2; ++nt)
        xva[t][nt] = *(const u64*)(xg0 +
            ((size_t)0 * 64 + n2 * 32 + nt * 16 + lm) * 1024 +
            p * 256 + (w * 4 + t) * 16 + quad * 4);
  }

  for (int s = 1; s <= CS; ++s) {
    const int cur = s & 1;
    const bool own = (s > 1);          // own slice comes from hprev regs
    f32x4 acc[4][2];

    if (layer == 0) {
      gather32(hx0 + (size_t)(s - 1) * SLOT, &Hl[cur][0][0], tid, n2, own, p, fast);
      if (own) {
#pragma unroll
        for (int nt = 0; nt < 2; ++nt)
          *(u64*)(&Hl[cur][0][(nt * 16 + lm) * 264 + jcol]) = hprev[nt];
      }
      // issue next step's xg loads AFTER the poll's vmcnt(0) rounds
      if (s < CS) {
#pragma unroll
        for (int t = 0; t < 4; ++t)
#pragma unroll
          for (int nt = 0; nt < 2; ++nt)
            xvb[t][nt] = *(const u64*)(xg0 +
                ((size_t)s * 64 + n2 * 32 + nt * 16 + lm) * 1024 +
                p * 256 + (w * 4 + t) * 16 + quad * 4);
      }
      wg_barrier();
#pragma unroll
      for (int t = 0; t < 4; ++t)
#pragma unroll
        for (int nt = 0; nt < 2; ++nt) {
          u64 v = xva[t][nt];
          f32x4 tt = { bf2f((u16)v), bf2f((u16)(v >> 16)),
                       bf2f((u16)(v >> 32)), bf2f((u16)(v >> 48)) };
          acc[t][nt] = tt;
        }
#pragma unroll
      for (int kc = 0; kc < 8; ++kc) {
        short8 b0[2];
#pragma unroll
        for (int nt = 0; nt < 2; ++nt)
          b0[nt] = *(const short8*)(&Hl[cur][0][(nt * 16 + lm) * 264 + kc * 32 + quad * 8]);
#pragma unroll
        for (int t = 0; t < 4; ++t)
#pragma unroll
          for (int nt = 0; nt < 2; ++nt)
            acc[t][nt] = __builtin_amdgcn_mfma_f32_16x16x32_bf16(
                wfh[t][kc], b0[nt], acc[t][nt], 0, 0, 0);
      }
    } else if (h0fast) {
      // ---- fast path: both gathers cheap, ONE barrier, merged chains ----
      gather32(hx1 + (size_t)(s - 1) * SLOT, &Hl[cur][1][0], tid, n2, own, p, fast);
      if (own) {
#pragma unroll
        for (int nt = 0; nt < 2; ++nt)
          *(u64*)(&Hl[cur][1][(nt * 16 + lm) * 264 + jcol]) = hprev[nt];
      }
      gather32(hx0 + (size_t)s * SLOT, &Hl[cur][0][0], tid, n2, false, p, true);
      wg_barrier();
#pragma unroll
      for (int t = 0; t < 4; ++t)
#pragma unroll
        for (int nt = 0; nt < 2; ++nt) acc[t][nt] = bias_f[t];
#pragma unroll
      for (int kc = 0; kc < 8; ++kc) {
        short8 b0[2];
#pragma unroll
        for (int nt = 0; nt < 2; ++nt)
          b0[nt] = *(const short8*)(&Hl[cur][0][(nt * 16 + lm) * 264 + kc * 32 + quad * 8]);
#pragma unroll
        for (int t = 0; t < 4; ++t)
#pragma unroll
          for (int nt = 0; nt < 2; ++nt)
            acc[t][nt] = __builtin_amdgcn_mfma_f32_16x16x32_bf16(
                wfi[t][kc], b0[nt], acc[t][nt], 0, 0, 0);
      }
#pragma unroll
      for (int kc = 0; kc < 8; ++kc) {
        short8 b1[2];
#pragma unroll
        for (int nt = 0; nt < 2; ++nt)
          b1[nt] = *(const short8*)(&Hl[cur][1][(nt * 16 + lm) * 264 + kc * 32 + quad * 8]);
#pragma unroll
        for (int t = 0; t < 4; ++t)
#pragma unroll
          for (int nt = 0; nt < 2; ++nt)
            acc[t][nt] = __builtin_amdgcn_mfma_f32_16x16x32_bf16(
                wfh[t][kc], b1[nt], acc[t][nt], 0, 0, 0);
      }
    } else {
      // ---- R8 path: h0 agent RT hidden under the W_hh chain ----
      gather32(hx1 + (size_t)(s - 1) * SLOT, &Hl[cur][1][0], tid, n2, own, p, fast);
      if (own) {
#pragma unroll
        for (int nt = 0; nt < 2; ++nt)
          *(u64*)(&Hl[cur][1][(nt * 16 + lm) * 264 + jcol]) = hprev[nt];
      }
      const u16* ah = hx0 + (size_t)s * SLOT +
                      ((size_t)(n2 * 32 + tw) * 256 + j4 * 4);
      u64 vh[8];
      ld8_issue(ah, vh);
      wg_barrier();
#pragma unroll
      for (int t = 0; t < 4; ++t)
#pragma unroll
        for (int nt = 0; nt < 2; ++nt) acc[t][nt] = bias_f[t];
#pragma unroll
      for (int kc = 0; kc < 8; ++kc) {
        short8 b1[2];
#pragma unroll
        for (int nt = 0; nt < 2; ++nt)
          b1[nt] = *(const short8*)(&Hl[cur][1][(nt * 16 + lm) * 264 + kc * 32 + quad * 8]);
#pragma unroll
        for (int t = 0; t < 4; ++t)
#pragma unroll
          for (int nt = 0; nt < 2; ++nt)
            acc[t][nt] = __builtin_amdgcn_mfma_f32_16x16x32_bf16(
                wfh[t][kc], b1[nt], acc[t][nt], 0, 0, 0);
      }
      vmwait8(vh);
      for (;;) {
        bool bad = false;
#pragma unroll
        for (int i = 0; i < 8; ++i) bad |= (vh[i] == SENT64);
        if (!bad) break;
        ld8_agent(ah, vh);
      }
#pragma unroll
      for (int i = 0; i < 8; ++i)
        *(u64*)(&Hl[cur][0][(i * 4 + tw) * 264 + j4 * 4]) = vh[i];
      wg_barrier();
#pragma unroll
      for (int kc = 0; kc < 8; ++kc) {
        short8 b0[2];
#pragma unroll
        for (int nt = 0; nt < 2; ++nt)
          b0[nt] = *(const short8*)(&Hl[cur][0][(nt * 16 + lm) * 264 + kc * 32 + quad * 8]);
#pragma unroll
        for (int t = 0; t < 4; ++t)
#pragma unroll
          for (int nt = 0; nt < 2; ++nt)
            acc[t][nt] = __builtin_amdgcn_mfma_f32_16x16x32_bf16(
                wfi[t][kc], b0[nt], acc[t][nt], 0, 0, 0);
      }
    }

    // ---- nonlinearity + dual-publish (plain -> shared L2, sc1 -> MALL) ----
    u16* hd = myhx + (size_t)s * SLOT;
#pragma unroll
    for (int nt = 0; nt < 2; ++nt) {
      u64 h = 0;
#pragma unroll
      for (int t = 0; t < 4; ++t) {
        float iv = sigf(acc[t][nt][0]);
        float fv = sigf(acc[t][nt][1]);
        float gv = tanhf_fast(acc[t][nt][2]);
        float ov = sigf(acc[t][nt][3]);
        float cv = fv * cst[t][nt] + iv * gv;
        cst[t][nt] = cv;
        h |= (u64)f2bf(ov * tanhf_fast(cv)) << (16 * t);
      }
      const int b = n2 * 32 + nt * 16 + lm;
      u16* pd = hd + (size_t)b * 256 + jcol;
      st_plain(pd, h);
      astore(pd, h);
      if (s == CS) {   // seed next chunk's slot0
        u16* ps = myhx + (size_t)b * 256 + jcol;
        st_plain(ps, h);
        astore(ps, h);
      }
      if (layer) *(u64*)(x2 + ((size_t)(s - 1) * 64 + b) * 256 + jcol) = h;
      hprev[nt] = h;
    }
    // rotate xg prefetch (loads issued pre-barrier have long completed)
    if (layer == 0 && s < CS) {
#pragma unroll
      for (int t = 0; t < 4; ++t)
#pragma unroll
        for (int nt = 0; nt < 2; ++nt) xva[t][nt] = xvb[t][nt];
    }
    // no end-of-step barrier: next step writes the other LDS parity.
  }
#pragma unroll
  for (int t = 0; t < 4; ++t) { cp[t * 2] = cst[t][0]; cp[t * 2 + 1] = cst[t][1]; }
}

// ---------------- launch ----------------
extern "C" void kernel_launch(void* const* d_in, const int* in_sizes, int n_in,
                              void* d_out, int out_size, void* d_ws, size_t ws_size,
                              hipStream_t stream)
{
  const float* in0   = (const float*)d_in[0];
  const float* enc_w = (const float*)d_in[1];
  const float* enc_b = (const float*)d_in[2];
  const float* w_ih  = (const float*)d_in[3];
  const float* w_hh  = (const float*)d_in[4];
  const float* b_ih  = (const float*)d_in[5];
  const float* b_hh  = (const float*)d_in[6];
  const float* dec_w = (const float*)d_in[7];
  const float* dec_b = (const float*)d_in[8];

  char* ws = (char*)d_ws;
  u16*   XG    = (u16*)(ws);                 // 16,777,216  xg0 chunk [CN][1024]
  u16*   X2    = (u16*)(ws + 16777216);      //  4,194,304  x2 chunk [CN][256]
  u16*   WHHP  = (u16*)(ws + 20971520);      //  1,048,576
  u16*   WIH1P = (u16*)(ws + 22020096);      //    524,288
  u16*   CW    = (u16*)(ws + 22544384);      //    131,072
  u16*   WDEC  = (u16*)(ws + 22675456);      //     32,768
  float* CB    = (float*)(ws + 22708224);    //      4,096
  float* B1P   = (float*)(ws + 22712320);    //      4,096
  u16*   HX0   = (u16*)(ws + 22716416);      //  4,227,072  [CS+1 slots][64][256]
  u16*   HX1   = (u16*)(ws + 26943488);      //  4,227,072
  float* CST   = (float*)(ws + 31170560);    //    131,072
  int*   RDV   = (int*)(ws + 31301632);      //        256  32 ids + ready ctr

  if (ws_size < 31301888) return;   // diagnostic guard

  // sentinel-fill both h histories, then prep zeroes slot0 (h(0)=0)
  hipMemsetAsync(HX0, 0x7F, HXBYTES, stream);
  hipMemsetAsync(HX1, 0x7F, HXBYTES, stream);

  prep_kernel<<<dim3((PREP_TOTAL + 255) / 256), 256, 0, stream>>>(
      enc_w, enc_b, w_ih, w_hh, b_ih, b_hh, dec_w,
      WDEC, CW, CB, B1P, WHHP, WIH1P, HX0, HX1, RDV);

  for (int c = 0; c < NCH; ++c) {
    const float* inc = in0 + (size_t)c * CN * 64;
    float* outc = (float*)d_out + (size_t)c * CN * 64;
    // xg0 = inc @ CW^T + CB  (encoder folded in; M=CN, N=1024, K=64)
    gemm_bt<1, 1, 1, 1><<<dim3(16, CN / 64), 256, 0, stream>>>(inc, CW, XG, CB, 1024);
    // fused 2-layer dataflow recurrence (32 blocks; 16 roles by rendezvous)
    lstm_fused<<<dim3(32), 256, 0, stream>>>(XG, X2, WHHP, WIH1P, B1P,
                                             HX0, HX1, CST, RDV, c * CS);
    // re-sentinel slots 1..CS for the next chunk (slot0 = fresh seed, keep)
    if (c + 1 < NCH) {
      hipMemsetAsync((char*)HX0 + SLOT * 2, 0x7F, HXBYTES - SLOT * 2, stream);
      hipMemsetAsync((char*)HX1 + SLOT * 2, 0x7F, HXBYTES - SLOT * 2, stream);
    }
    // decoder: outc = x2 @ dec_w^T + dec_b  (M=CN, N=64, K=256), fp32 out
    gemm_bt<4, 0, 1, 0><<<dim3(1, CN / 64), 256, 0, stream>>>(X2, WDEC, (void*)outc, dec_b, 64);
  }

  (void)in_sizes; (void)n_in; (void)out_size;
}

// Round 7
// 11300.523 us; speedup vs baseline: 1.0850x; 1.0850x over previous
//
#include <hip/hip_runtime.h>

// LSTM_15556371546645 — MI355X (gfx950), round 13
// R12 = R8 (proven, 7554us) + L0 fragment-direct exchange, made SOUND:
//  - R11 NaN mechanism: compiler spill/copy of a register that is the
//    destination of an in-flight asm load saves pre-load garbage. Deferred
//    waits across C++ code are only safe if nothing touches those regs.
//  - Fix: L0 polls its 16 MFMA B-fragments with SINGLE-BLOCK asm
//    (16 x global_load_dwordx4 sc0 sc1 + s_waitcnt vmcnt(0) in one block) —
//    values final at block exit; any later spill is of a final value.
//  - L0: no LDS, no barriers, waves independent. Removes LDS write + lgkm
//    drain + max-of-4-waves barrier + ds_read from the ring-critical L0
//    cadence (L0 step s depends on L0 step s-1 -> sets pipeline rate).
//  - L1: byte-for-byte the R8-proven path (LDS h1 gather + deferred 8B h0
//    issue under the W_hh chain; 208-VGPR profile that did not spill).

typedef unsigned short u16;
typedef unsigned long long u64;
typedef __attribute__((ext_vector_type(8))) short short8;   // 8 x bf16
typedef __attribute__((ext_vector_type(4))) float f32x4;    // MFMA acc
typedef __attribute__((ext_vector_type(4))) unsigned int u32x4;

#define SEQ  2048
#define CS   128            // chunk steps
#define NCH  (SEQ / CS)     // 16 chunks
#define CN   (CS * 64)      // rows per chunk = 8192
#define SLOT 16384          // u16 per h slot (64 b x 256 j)
#define HXBYTES ((size_t)(CS + 1) * SLOT * 2)   // 4,227,072 B per layer
#define SENT64 0x7F7F7F7F7F7F7F7FULL
#define S32    0x7F7F7F7Fu

// ---------------- numeric helpers ----------------
__device__ __forceinline__ u16 f2bf(float f) {
  unsigned u = __float_as_uint(f);
  unsigned r = u + 0x7fffu + ((u >> 16) & 1u);   // RTNE
  return (u16)(r >> 16);
}
__device__ __forceinline__ float bf2f(u16 h) {
  return __uint_as_float(((unsigned)h) << 16);
}
__device__ __forceinline__ float sigf(float x) {
  return __builtin_amdgcn_rcpf(1.f + __expf(-x));
}
__device__ __forceinline__ float tanhf_fast(float x) {
  return 1.f - 2.f * __builtin_amdgcn_rcpf(1.f + __expf(2.f * x));
}

__device__ __forceinline__ void astore(u16* p, u64 v) {
  __hip_atomic_store((u64*)p, v, __ATOMIC_RELAXED, __HIP_MEMORY_SCOPE_AGENT);
}

// ---- 8B poll loads (layer-1 path, R8-proven) ----
__device__ __forceinline__ void ld8_issue(const u16* a0, u64 v[8]) {
  asm volatile(
      "global_load_dwordx2 %0, %8, off sc0 sc1\n\t"
      "global_load_dwordx2 %1, %8, off offset:2048 sc0 sc1\n\t"
      "global_load_dwordx2 %2, %9, off sc0 sc1\n\t"
      "global_load_dwordx2 %3, %9, off offset:2048 sc0 sc1\n\t"
      "global_load_dwordx2 %4, %10, off sc0 sc1\n\t"
      "global_load_dwordx2 %5, %10, off offset:2048 sc0 sc1\n\t"
      "global_load_dwordx2 %6, %11, off sc0 sc1\n\t"
      "global_load_dwordx2 %7, %11, off offset:2048 sc0 sc1"
      : "=&v"(v[0]), "=&v"(v[1]), "=&v"(v[2]), "=&v"(v[3]),
        "=&v"(v[4]), "=&v"(v[5]), "=&v"(v[6]), "=&v"(v[7])
      : "v"(a0), "v"(a0 + 2048), "v"(a0 + 4096), "v"(a0 + 6144)
      : "memory");
}
__device__ __forceinline__ void vmwait8(u64 v[8]) {
  asm volatile("s_waitcnt vmcnt(0)"
      : "+v"(v[0]), "+v"(v[1]), "+v"(v[2]), "+v"(v[3]),
        "+v"(v[4]), "+v"(v[5]), "+v"(v[6]), "+v"(v[7]) :: "memory");
}
__device__ __forceinline__ void ld8_agent(const u16* a0, u64 v[8]) {
  ld8_issue(a0, v);
  vmwait8(v);
}

// ---- 16B fragment drain-load: ISSUE + WAIT IN ONE ASM BLOCK (sound) ----
// 16 fragments = rows lm and lm+16 of the 32-row slab, cols kc*32 u16.
__device__ __forceinline__ void ldf16_drain(const u16* a0, const u16* a1, u32x4 f[16]) {
  asm volatile(
      "global_load_dwordx4 %0, %16, off sc0 sc1\n\t"
      "global_load_dwordx4 %1, %16, off offset:64 sc0 sc1\n\t"
      "global_load_dwordx4 %2, %16, off offset:128 sc0 sc1\n\t"
      "global_load_dwordx4 %3, %16, off offset:192 sc0 sc1\n\t"
      "global_load_dwordx4 %4, %16, off offset:256 sc0 sc1\n\t"
      "global_load_dwordx4 %5, %16, off offset:320 sc0 sc1\n\t"
      "global_load_dwordx4 %6, %16, off offset:384 sc0 sc1\n\t"
      "global_load_dwordx4 %7, %16, off offset:448 sc0 sc1\n\t"
      "global_load_dwordx4 %8, %17, off sc0 sc1\n\t"
      "global_load_dwordx4 %9, %17, off offset:64 sc0 sc1\n\t"
      "global_load_dwordx4 %10, %17, off offset:128 sc0 sc1\n\t"
      "global_load_dwordx4 %11, %17, off offset:192 sc0 sc1\n\t"
      "global_load_dwordx4 %12, %17, off offset:256 sc0 sc1\n\t"
      "global_load_dwordx4 %13, %17, off offset:320 sc0 sc1\n\t"
      "global_load_dwordx4 %14, %17, off offset:384 sc0 sc1\n\t"
      "global_load_dwordx4 %15, %17, off offset:448 sc0 sc1\n\t"
      "s_waitcnt vmcnt(0)"
      : "=&v"(f[0]),  "=&v"(f[1]),  "=&v"(f[2]),  "=&v"(f[3]),
        "=&v"(f[4]),  "=&v"(f[5]),  "=&v"(f[6]),  "=&v"(f[7]),
        "=&v"(f[8]),  "=&v"(f[9]),  "=&v"(f[10]), "=&v"(f[11]),
        "=&v"(f[12]), "=&v"(f[13]), "=&v"(f[14]), "=&v"(f[15])
      : "v"(a0), "v"(a1)
      : "memory");
}
// Drain-style poll: each round is a complete single-block load+wait. A u32
// equal to 0x7F7F7F7F is unreachable for |h|<1 bf16 pairs -> sentinel.
__device__ __forceinline__ void pollf16_drain(const u16* a0, const u16* a1, u32x4 f[16]) {
  for (;;) {
    ldf16_drain(a0, a1, f);
    unsigned bad = 0;
#pragma unroll
    for (int i = 0; i < 16; ++i)
      bad |= (f[i].x == S32) | (f[i].y == S32) | (f[i].z == S32) | (f[i].w == S32);
    if (!bad) return;
  }
}

__device__ __forceinline__ void wg_barrier() {
  __builtin_amdgcn_sched_barrier(0);
  asm volatile("s_waitcnt lgkmcnt(0)" ::: "memory");
  __builtin_amdgcn_s_barrier();
  __builtin_amdgcn_sched_barrier(0);
}

// Row permutation: row' = p*256 + T*16 + u (T=0..15,u=0..15)
// gate g=u&3; j=(T>>2)*16+((u>>2)<<2)+(T&3); r_orig=g*256+p*64+j  [HW-verified R3]
__device__ __forceinline__ int rowp_to_orig(int rowp) {
  int p = rowp >> 8, T = (rowp >> 4) & 15, u = rowp & 15;
  int g = u & 3;
  int j = ((T >> 2) << 4) + ((u >> 2) << 2) + (T & 3);
  return g * 256 + p * 64 + j;
}

// ---------------- prep ----------------
#define PREP_TOTAL (16384 + 65536 + 1024 + 1024 + 524288 + 262144 + 32768)

__global__ void prep_kernel(const float* __restrict__ enc_w, const float* __restrict__ enc_b,
                            const float* __restrict__ w_ih, const float* __restrict__ w_hh,
                            const float* __restrict__ b_ih, const float* __restrict__ b_hh,
                            const float* __restrict__ dec_w,
                            u16* __restrict__ WDEC, u16* __restrict__ CW,
                            float* __restrict__ CB, float* __restrict__ B1P,
                            u16* __restrict__ WHHP, u16* __restrict__ WIH1P,
                            u16* __restrict__ HX0, u16* __restrict__ HX1)
{
  size_t idx = (size_t)blockIdx.x * 256 + threadIdx.x;
  if (idx < 16384) { WDEC[idx] = f2bf(dec_w[idx]); return; }
  idx -= 16384;
  if (idx < 65536) {
    int rowp = (int)(idx >> 6), f = (int)(idx & 63);
    int r = rowp_to_orig(rowp);
    float a = 0.f;
    for (int k = 0; k < 256; ++k) a += w_ih[r * 256 + k] * enc_w[k * 64 + f];
    CW[idx] = f2bf(a);
    return;
  }
  idx -= 65536;
  if (idx < 1024) {
    int r = rowp_to_orig((int)idx);
    float a = b_ih[r] + b_hh[r];
    for (int k = 0; k < 256; ++k) a += w_ih[r * 256 + k] * enc_b[k];
    CB[idx] = a;
    return;
  }
  idx -= 1024;
  if (idx < 1024) {
    int r = rowp_to_orig((int)idx);
    B1P[idx] = b_ih[1024 + r] + b_hh[1024 + r];
    return;
  }
  idx -= 1024;
  if (idx < 524288) {   // WHHP: flat = ((((l*4+p)*4+w)*4+t)*8+kc)*512 + lane*8 + e
    int l = (int)(idx >> 18);
    int rem = (int)(idx & 262143);
    int e = rem & 7, lane = (rem >> 3) & 63, kc = (rem >> 9) & 7;
    int t = (rem >> 12) & 3, wv = (rem >> 14) & 3, pp = (rem >> 16) & 3;
    int u = lane & 15, qd = lane >> 4;
    int g = u & 3;
    int j = wv * 16 + ((u >> 2) << 2) + t;
    int r = g * 256 + pp * 64 + j;
    int k = kc * 32 + qd * 8 + e;
    WHHP[idx] = f2bf(w_hh[(size_t)l * 262144 + (size_t)r * 256 + k]);
    return;
  }
  idx -= 524288;
  if (idx < 262144) {   // WIH1P (l=1)
    int rem = (int)idx;
    int e = rem & 7, lane = (rem >> 3) & 63, kc = (rem >> 9) & 7;
    int t = (rem >> 12) & 3, wv = (rem >> 14) & 3, pp = (rem >> 16) & 3;
    int u = lane & 15, qd = lane >> 4;
    int g = u & 3;
    int j = wv * 16 + ((u >> 2) << 2) + t;
    int r = g * 256 + pp * 64 + j;
    int k = kc * 32 + qd * 8 + e;
    WIH1P[idx] = f2bf(w_ih[262144 + (size_t)r * 256 + k]);
    return;
  }
  idx -= 262144;
  if (idx < 32768) {    // zero slot0 (overwrites the 0x7F memset)
    if (idx < 16384) HX0[idx] = 0;
    else             HX1[idx - 16384] = 0;
  }
}

// ---------------- generic bf16 GEMM:  C(MxN) = A(MxK) * B(NxK)^T + bias ----------------
template<int KTILES, int OUTBF, int BMODE, int AF32>
__global__ __launch_bounds__(256, 1) void gemm_bt(
    const void* __restrict__ Av, const u16* __restrict__ B, void* __restrict__ Cv,
    const float* __restrict__ bias, size_t ldc)
{
  constexpr int K = KTILES * 64;
  __shared__ __align__(16) u16 Asl[64 * 72];
  __shared__ __align__(16) u16 Bsl[64 * 72];
  const int tid = threadIdx.x;
  const int w = tid >> 6, lane = tid & 63, lm = lane & 15, quad = lane >> 4;
  const size_t m0 = (size_t)blockIdx.y * 64, n0 = (size_t)blockIdx.x * 64;

  f32x4 acc[4];
#pragma unroll
  for (int nt = 0; nt < 4; ++nt) { f32x4 z = {0.f, 0.f, 0.f, 0.f}; acc[nt] = z; }

  for (int kb = 0; kb < KTILES; ++kb) {
    if (AF32) {
      const float* Af = (const float*)Av;
#pragma unroll
      for (int c = 0; c < 4; ++c) {
        int idx = c * 256 + tid;
        int row = idx >> 4, k4 = idx & 15;
        float4 v = *(const float4*)(Af + (m0 + row) * (size_t)K + kb * 64 + k4 * 4);
        u64 pv = (u64)f2bf(v.x) | ((u64)f2bf(v.y) << 16) |
                 ((u64)f2bf(v.z) << 32) | ((u64)f2bf(v.w) << 48);
        *(u64*)(&Asl[row * 72 + k4 * 4]) = pv;
      }
    } else {
      const u16* Ab = (const u16*)Av;
#pragma unroll
      for (int c = 0; c < 2; ++c) {
        int idx = c * 256 + tid;
        int row = idx >> 3, k8 = idx & 7;
        *(uint4*)(&Asl[row * 72 + k8 * 8]) =
            *(const uint4*)(Ab + (m0 + row) * (size_t)K + kb * 64 + k8 * 8);
      }
    }
#pragma unroll
    for (int c = 0; c < 2; ++c) {
      int idx = c * 256 + tid;
      int row = idx >> 3, k8 = idx & 7;
      *(uint4*)(&Bsl[row * 72 + k8 * 8]) =
          *(const uint4*)(B + (n0 + row) * (size_t)K + kb * 64 + k8 * 8);
    }
    __syncthreads();
#pragma unroll
    for (int kc = 0; kc < 2; ++kc) {
      short8 a = *(const short8*)(&Asl[(w * 16 + lm) * 72 + kc * 32 + quad * 8]);
#pragma unroll
      for (int nt = 0; nt < 4; ++nt) {
        short8 b = *(const short8*)(&Bsl[(nt * 16 + lm) * 72 + kc * 32 + quad * 8]);
        acc[nt] = __builtin_amdgcn_mfma_f32_16x16x32_bf16(a, b, acc[nt], 0, 0, 0);
      }
    }
    __syncthreads();
  }
#pragma unroll
  for (int nt = 0; nt < 4; ++nt) {
    size_t n = n0 + nt * 16 + lm;
    float bn = (BMODE == 1) ? bias[n] : 0.f;
#pragma unroll
    for (int r = 0; r < 4; ++r) {
      size_t m = m0 + w * 16 + quad * 4 + r;
      float v = acc[nt][r] + ((BMODE == 2) ? bias[m] : bn);
      if (OUTBF) ((u16*)Cv)[m * ldc + n] = f2bf(v);
      else       ((float*)Cv)[m * ldc + n] = v;
    }
  }
}

// ---------------- sentinel-poll gather (R8-proven): 32 b x 256 j slab -> LDS ----------------
__device__ __forceinline__ void gather32(const u16* __restrict__ src,
                                         u16* __restrict__ dst,
                                         int tid, int n2, bool skip, int p)
{
  const int j4 = tid & 63;
  const int tw = tid >> 6;
  if (skip && ((j4 >> 4) == p)) return;
  const u16* a0 = src + ((size_t)(n2 * 32 + tw) * 256 + j4 * 4);
  u64 v[8];
  ld8_agent(a0, v);
  for (;;) {
    bool bad = false;
#pragma unroll
    for (int i = 0; i < 8; ++i) bad |= (v[i] == SENT64);
    if (!bad) break;
    ld8_agent(a0, v);
  }
#pragma unroll
  for (int i = 0; i < 8; ++i)
    *(u64*)(dst + (i * 4 + tw) * 264 + j4 * 4) = v[i];
}

// ---------------- fused 2-layer dataflow recurrence (16 wgs, agent scope) ----------------
// role = blockIdx.x: layer = role>>3, p = role&3, n2 = (role>>2)&1.
// hx layout: [slot 0..CS][64 b][256 j] u16; slot s holds h(base+s); slot0 = h(base).
__global__ __launch_bounds__(256, 1) void lstm_fused(
    const u16* __restrict__ xg0, u16* __restrict__ x2,
    const u16* __restrict__ whhp, const u16* __restrict__ wih1p,
    const float* __restrict__ b1p,
    u16* __restrict__ hx0, u16* __restrict__ hx1,
    float* __restrict__ cstb, int base)
{
  __shared__ __align__(16) u16 Hl[2][2][32 * 264];   // [parity][buf]; L1 only
  const int tid = threadIdx.x;
  const int role = blockIdx.x;
  const int layer = role >> 3, p = role & 3, n2 = (role >> 2) & 1;
  const int lane = tid & 63, w = tid >> 6, lm = lane & 15, quad = lane >> 4;
  const int j4 = tid & 63, tw = tid >> 6;

  // ---- weights into VGPR fragments ----
  short8 wfh[4][8], wfi[4][8];
  {
    const u16* wp = whhp + (size_t)((layer * 4 + p) * 4 + w) * 16384 + lane * 8;
#pragma unroll
    for (int t = 0; t < 4; ++t)
#pragma unroll
      for (int kc = 0; kc < 8; ++kc)
        wfh[t][kc] = *(const short8*)(wp + (t * 8 + kc) * 512);
  }
  f32x4 bias_f[4];
  if (layer) {
    const u16* wp = wih1p + (size_t)(p * 4 + w) * 16384 + lane * 8;
#pragma unroll
    for (int t = 0; t < 4; ++t)
#pragma unroll
      for (int kc = 0; kc < 8; ++kc)
        wfi[t][kc] = *(const short8*)(wp + (t * 8 + kc) * 512);
#pragma unroll
    for (int t = 0; t < 4; ++t)
      bias_f[t] = *(const f32x4*)(b1p + p * 256 + (w * 4 + t) * 16 + quad * 4);
  }

  float* cp = cstb + (size_t)(((layer * 4 + p) * 2 + n2) * 256 + tid) * 8;
  float cst[4][2];
  if (base) {
#pragma unroll
    for (int t = 0; t < 4; ++t) { cst[t][0] = cp[t * 2]; cst[t][1] = cp[t * 2 + 1]; }
  } else {
#pragma unroll
    for (int t = 0; t < 4; ++t) { cst[t][0] = 0.f; cst[t][1] = 0.f; }
  }

  const int jcol = p * 64 + w * 16 + quad * 4;
  u16* myhx = layer ? hx1 : hx0;
  u64 hprev[2] = {0, 0};
  // fragment base offset within a slot: row n2*32+lm, col quad*8
  const size_t fro = ((size_t)(n2 * 32 + lm) * 256 + quad * 8);

  for (int s = 1; s <= CS; ++s) {
    const int cur = s & 1;
    const bool own = (s > 1);
    f32x4 acc[4][2];

    if (layer == 0) {
      // ---- barrier-free, LDS-free: direct fragment poll of h0(s-1) ----
      u64 xv[4][2];
#pragma unroll
      for (int t = 0; t < 4; ++t)
#pragma unroll
        for (int nt = 0; nt < 2; ++nt)
          xv[t][nt] = *(const u64*)(xg0 +
              ((size_t)(s - 1) * 64 + n2 * 32 + nt * 16 + lm) * 1024 +
              p * 256 + (w * 4 + t) * 16 + quad * 4);
      const u16* fb0 = hx0 + (size_t)(s - 1) * SLOT + fro;
      const u16* fb1 = fb0 + 16 * 256;
      u32x4 fr[16];
      pollf16_drain(fb0, fb1, fr);
#pragma unroll
      for (int t = 0; t < 4; ++t)
#pragma unroll
        for (int nt = 0; nt < 2; ++nt) {
          u64 v = xv[t][nt];
          f32x4 tt = { bf2f((u16)v), bf2f((u16)(v >> 16)),
                       bf2f((u16)(v >> 32)), bf2f((u16)(v >> 48)) };
          acc[t][nt] = tt;
        }
#pragma unroll
      for (int kc = 0; kc < 8; ++kc) {
        short8 b0 = __builtin_bit_cast(short8, fr[kc]);
        short8 b1 = __builtin_bit_cast(short8, fr[8 + kc]);
#pragma unroll
        for (int t = 0; t < 4; ++t) {
          acc[t][0] = __builtin_amdgcn_mfma_f32_16x16x32_bf16(wfh[t][kc], b0, acc[t][0], 0, 0, 0);
          acc[t][1] = __builtin_amdgcn_mfma_f32_16x16x32_bf16(wfh[t][kc], b1, acc[t][1], 0, 0, 0);
        }
      }
    } else {
      // ---- R8 path, unchanged ----
      // (a) h1(s-1) gather (stale by a full step; own slice from regs)
      gather32(hx1 + (size_t)(s - 1) * SLOT, &Hl[cur][1][0], tid, n2, own, p);
      if (own) {
#pragma unroll
        for (int nt = 0; nt < 2; ++nt)
          *(u64*)(&Hl[cur][1][(nt * 16 + lm) * 264 + jcol]) = hprev[nt];
      }
      // (b) issue fresh h0(s) first-round loads; fly under barrier + W_hh chain
      const u16* ah = hx0 + (size_t)s * SLOT +
                      ((size_t)(n2 * 32 + tw) * 256 + j4 * 4);
      u64 vh[8];
      ld8_issue(ah, vh);
      wg_barrier();
      // (c) acc = bias; W_hh x h1(s-1) chain
#pragma unroll
      for (int t = 0; t < 4; ++t)
#pragma unroll
        for (int nt = 0; nt < 2; ++nt) acc[t][nt] = bias_f[t];
#pragma unroll
      for (int kc = 0; kc < 8; ++kc) {
        short8 b1[2];
#pragma unroll
        for (int nt = 0; nt < 2; ++nt)
          b1[nt] = *(const short8*)(&Hl[cur][1][(nt * 16 + lm) * 264 + kc * 32 + quad * 8]);
#pragma unroll
        for (int t = 0; t < 4; ++t)
#pragma unroll
          for (int nt = 0; nt < 2; ++nt)
            acc[t][nt] = __builtin_amdgcn_mfma_f32_16x16x32_bf16(
                wfh[t][kc], b1[nt], acc[t][nt], 0, 0, 0);
      }
      // (d) wait on in-flight h0 loads; retry only if truly late
      vmwait8(vh);
      for (;;) {
        bool bad = false;
#pragma unroll
        for (int i = 0; i < 8; ++i) bad |= (vh[i] == SENT64);
        if (!bad) break;
        ld8_agent(ah, vh);
      }
#pragma unroll
      for (int i = 0; i < 8; ++i)
        *(u64*)(&Hl[cur][0][(i * 4 + tw) * 264 + j4 * 4]) = vh[i];
      wg_barrier();
      // (e) W_ih x h0(s) chain
#pragma unroll
      for (int kc = 0; kc < 8; ++kc) {
        short8 b0[2];
#pragma unroll
        for (int nt = 0; nt < 2; ++nt)
          b0[nt] = *(const short8*)(&Hl[cur][0][(nt * 16 + lm) * 264 + kc * 32 + quad * 8]);
#pragma unroll
        for (int t = 0; t < 4; ++t)
#pragma unroll
          for (int nt = 0; nt < 2; ++nt)
            acc[t][nt] = __builtin_amdgcn_mfma_f32_16x16x32_bf16(
                wfi[t][kc], b0[nt], acc[t][nt], 0, 0, 0);
      }
    }

    // ---- nonlinearity + fire-and-forget publish (no drain, no flag) ----
    u16* hd = myhx + (size_t)s * SLOT;
#pragma unroll
    for (int nt = 0; nt < 2; ++nt) {
      u64 h = 0;
#pragma unroll
      for (int t = 0; t < 4; ++t) {
        float iv = sigf(acc[t][nt][0]);
        float fv = sigf(acc[t][nt][1]);
        float gv = tanhf_fast(acc[t][nt][2]);
        float ov = sigf(acc[t][nt][3]);
        float cv = fv * cst[t][nt] + iv * gv;
        cst[t][nt] = cv;
        h |= (u64)f2bf(ov * tanhf_fast(cv)) << (16 * t);
      }
      const int b = n2 * 32 + nt * 16 + lm;
      astore(hd + (size_t)b * 256 + jcol, h);
      if (s == CS) astore(myhx + (size_t)b * 256 + jcol, h);   // seed next chunk
      if (layer) *(u64*)(x2 + ((size_t)(s - 1) * 64 + b) * 256 + jcol) = h;
      hprev[nt] = h;
    }
    // layer 1: no end-of-step barrier (next step uses the other LDS parity).
  }
#pragma unroll
  for (int t = 0; t < 4; ++t) { cp[t * 2] = cst[t][0]; cp[t * 2 + 1] = cst[t][1]; }
}

// ---------------- launch ----------------
extern "C" void kernel_launch(void* const* d_in, const int* in_sizes, int n_in,
                              void* d_out, int out_size, void* d_ws, size_t ws_size,
                              hipStream_t stream)
{
  const float* in0   = (const float*)d_in[0];
  const float* enc_w = (const float*)d_in[1];
  const float* enc_b = (const float*)d_in[2];
  const float* w_ih  = (const float*)d_in[3];
  const float* w_hh  = (const float*)d_in[4];
  const float* b_ih  = (const float*)d_in[5];
  const float* b_hh  = (const float*)d_in[6];
  const float* dec_w = (const float*)d_in[7];
  const float* dec_b = (const float*)d_in[8];

  char* ws = (char*)d_ws;
  u16*   XG    = (u16*)(ws);                 // 16,777,216  xg0 chunk [CN][1024]
  u16*   X2    = (u16*)(ws + 16777216);      //  4,194,304  x2 chunk [CN][256]
  u16*   WHHP  = (u16*)(ws + 20971520);      //  1,048,576
  u16*   WIH1P = (u16*)(ws + 22020096);      //    524,288
  u16*   CW    = (u16*)(ws + 22544384);      //    131,072
  u16*   WDEC  = (u16*)(ws + 22675456);      //     32,768
  float* CB    = (float*)(ws + 22708224);    //      4,096
  float* B1P   = (float*)(ws + 22712320);    //      4,096
  u16*   HX0   = (u16*)(ws + 22716416);      //  4,227,072  [CS+1 slots][64][256]
  u16*   HX1   = (u16*)(ws + 26943488);      //  4,227,072
  float* CST   = (float*)(ws + 31170560);    //    131,072

  if (ws_size < 31301632) return;   // diagnostic guard

  // sentinel-fill both h histories, then prep zeroes slot0 (h(0)=0)
  hipMemsetAsync(HX0, 0x7F, HXBYTES, stream);
  hipMemsetAsync(HX1, 0x7F, HXBYTES, stream);

  prep_kernel<<<dim3((PREP_TOTAL + 255) / 256), 256, 0, stream>>>(
      enc_w, enc_b, w_ih, w_hh, b_ih, b_hh, dec_w,
      WDEC, CW, CB, B1P, WHHP, WIH1P, HX0, HX1);

  for (int c = 0; c < NCH; ++c) {
    const float* inc = in0 + (size_t)c * CN * 64;
    float* outc = (float*)d_out + (size_t)c * CN * 64;
    // xg0 = inc @ CW^T + CB  (encoder folded in; M=CN, N=1024, K=64)
    gemm_bt<1, 1, 1, 1><<<dim3(16, CN / 64), 256, 0, stream>>>(inc, CW, XG, CB, 1024);
    // fused 2-layer dataflow recurrence
    lstm_fused<<<dim3(16), 256, 0, stream>>>(XG, X2, WHHP, WIH1P, B1P,
                                             HX0, HX1, CST, c * CS);
    // re-sentinel slots 1..CS for the next chunk (slot0 = fresh seed, keep)
    if (c + 1 < NCH) {
      hipMemsetAsync((char*)HX0 + SLOT * 2, 0x7F, HXBYTES - SLOT * 2, stream);
      hipMemsetAsync((char*)HX1 + SLOT * 2, 0x7F, HXBYTES - SLOT * 2, stream);
    }
    // decoder: outc = x2 @ dec_w^T + dec_b  (M=CN, N=64, K=256), fp32 out
    gemm_bt<4, 0, 1, 0><<<dim3(1, CN / 64), 256, 0, stream>>>(X2, WDEC, (void*)outc, dec_b, 64);
  }

  (void)in_sizes; (void)n_in; (void)out_size;
}

// Round 8
// 7441.758 us; speedup vs baseline: 1.6476x; 1.5185x over previous
//
#include <hip/hip_runtime.h>

// LSTM_15556371546645 — MI355X (gfx950), round 14
// R13 = R8 (proven best, 7554us) + SOUND in-asm pipelined sentinel polls.
//  - R12 post-mortem: fragment drain-poll doubled FETCH (24.7->45.3GB) and
//    kept RT-spaced rounds -> regressed. L0 reverted to R8 gather.
//  - R10's counted-wait idea, made sound: the ENTIRE poll loop lives in one
//    asm block: prime 8 loads; loop { reissue 8 into the SAME regs;
//    s_waitcnt vmcnt(8) (previous round final); v_cmp_eq_u64 sentinel check;
//    s_cbranch }. Same-reg reissue is benign: slot words are write-once, a
//    newer load of the same address returns the same-or-final value. The
//    compiler cannot inject VMEM inside the block; older astores only make
//    vmcnt(8) conservative; exec-masked lanes contribute 0 to vcc so the
//    scalar branch is correct under partial-lane skip. Final vmcnt(0)
//    drains the trailing round -> regs final at block exit (R11 lesson).
//  - Check-to-check spacing: ~RT -> ~RT/2; poll VALU spin eliminated.
// Numerics bitwise-identical to R8.

typedef unsigned short u16;
typedef unsigned long long u64;
typedef __attribute__((ext_vector_type(8))) short short8;   // 8 x bf16
typedef __attribute__((ext_vector_type(4))) float f32x4;    // MFMA acc

#define SEQ  2048
#define CS   128            // chunk steps
#define NCH  (SEQ / CS)     // 16 chunks
#define CN   (CS * 64)      // rows per chunk = 8192
#define SLOT 16384          // u16 per h slot (64 b x 256 j)
#define HXBYTES ((size_t)(CS + 1) * SLOT * 2)   // 4,227,072 B per layer
#define SENT64 0x7F7F7F7F7F7F7F7FULL

// ---------------- numeric helpers ----------------
__device__ __forceinline__ u16 f2bf(float f) {
  unsigned u = __float_as_uint(f);
  unsigned r = u + 0x7fffu + ((u >> 16) & 1u);   // RTNE
  return (u16)(r >> 16);
}
__device__ __forceinline__ float bf2f(u16 h) {
  return __uint_as_float(((unsigned)h) << 16);
}
__device__ __forceinline__ float sigf(float x) {
  return __builtin_amdgcn_rcpf(1.f + __expf(-x));
}
__device__ __forceinline__ float tanhf_fast(float x) {
  return 1.f - 2.f * __builtin_amdgcn_rcpf(1.f + __expf(2.f * x));
}

__device__ __forceinline__ void astore(u16* p, u64 v) {
  __hip_atomic_store((u64*)p, v, __ATOMIC_RELAXED, __HIP_MEMORY_SCOPE_AGENT);
}

// ---- deferred-issue 8x8B agent loads (L1 h0 hop; R8-proven profile) ----
__device__ __forceinline__ void ld8_issue(const u16* a0, u64 v[8]) {
  asm volatile(
      "global_load_dwordx2 %0, %8, off sc0 sc1\n\t"
      "global_load_dwordx2 %1, %8, off offset:2048 sc0 sc1\n\t"
      "global_load_dwordx2 %2, %9, off sc0 sc1\n\t"
      "global_load_dwordx2 %3, %9, off offset:2048 sc0 sc1\n\t"
      "global_load_dwordx2 %4, %10, off sc0 sc1\n\t"
      "global_load_dwordx2 %5, %10, off offset:2048 sc0 sc1\n\t"
      "global_load_dwordx2 %6, %11, off sc0 sc1\n\t"
      "global_load_dwordx2 %7, %11, off offset:2048 sc0 sc1"
      : "=&v"(v[0]), "=&v"(v[1]), "=&v"(v[2]), "=&v"(v[3]),
        "=&v"(v[4]), "=&v"(v[5]), "=&v"(v[6]), "=&v"(v[7])
      : "v"(a0), "v"(a0 + 2048), "v"(a0 + 4096), "v"(a0 + 6144)
      : "memory");
}
__device__ __forceinline__ void vmwait8(u64 v[8]) {
  asm volatile("s_waitcnt vmcnt(0)"
      : "+v"(v[0]), "+v"(v[1]), "+v"(v[2]), "+v"(v[3]),
        "+v"(v[4]), "+v"(v[5]), "+v"(v[6]), "+v"(v[7]) :: "memory");
}

// ---- SOUND pipelined sentinel poll: whole loop in one asm block ----
// 8 rows at stride 2048B from a0. Two rounds in flight targeting the SAME
// registers (benign write-once rewrite); vmcnt(8) => previous round final;
// v_cmp_eq_u64 vs sentinel, wave-uniform s_cbranch; final vmcnt(0) drain.
__device__ __forceinline__ void poll8(const u16* a0, u64 v[8]) {
  u64 sacc;
  asm volatile(
      "global_load_dwordx2 %0, %9, off sc0 sc1\n\t"
      "global_load_dwordx2 %1, %9, off offset:2048 sc0 sc1\n\t"
      "global_load_dwordx2 %2, %10, off sc0 sc1\n\t"
      "global_load_dwordx2 %3, %10, off offset:2048 sc0 sc1\n\t"
      "global_load_dwordx2 %4, %11, off sc0 sc1\n\t"
      "global_load_dwordx2 %5, %11, off offset:2048 sc0 sc1\n\t"
      "global_load_dwordx2 %6, %12, off sc0 sc1\n\t"
      "global_load_dwordx2 %7, %12, off offset:2048 sc0 sc1\n\t"
      "P%=:\n\t"
      "global_load_dwordx2 %0, %9, off sc0 sc1\n\t"
      "global_load_dwordx2 %1, %9, off offset:2048 sc0 sc1\n\t"
      "global_load_dwordx2 %2, %10, off sc0 sc1\n\t"
      "global_load_dwordx2 %3, %10, off offset:2048 sc0 sc1\n\t"
      "global_load_dwordx2 %4, %11, off sc0 sc1\n\t"
      "global_load_dwordx2 %5, %11, off offset:2048 sc0 sc1\n\t"
      "global_load_dwordx2 %6, %12, off sc0 sc1\n\t"
      "global_load_dwordx2 %7, %12, off offset:2048 sc0 sc1\n\t"
      "s_waitcnt vmcnt(8)\n\t"
      "v_cmp_eq_u64 vcc, %13, %0\n\t"
      "s_mov_b64 %8, vcc\n\t"
      "v_cmp_eq_u64 vcc, %13, %1\n\t"
      "s_or_b64 %8, %8, vcc\n\t"
      "v_cmp_eq_u64 vcc, %13, %2\n\t"
      "s_or_b64 %8, %8, vcc\n\t"
      "v_cmp_eq_u64 vcc, %13, %3\n\t"
      "s_or_b64 %8, %8, vcc\n\t"
      "v_cmp_eq_u64 vcc, %13, %4\n\t"
      "s_or_b64 %8, %8, vcc\n\t"
      "v_cmp_eq_u64 vcc, %13, %5\n\t"
      "s_or_b64 %8, %8, vcc\n\t"
      "v_cmp_eq_u64 vcc, %13, %6\n\t"
      "s_or_b64 %8, %8, vcc\n\t"
      "v_cmp_eq_u64 vcc, %13, %7\n\t"
      "s_or_b64 %8, %8, vcc\n\t"
      "s_cmp_lg_u64 %8, 0\n\t"
      "s_cbranch_scc1 P%=\n\t"
      "s_waitcnt vmcnt(0)"
      : "=&v"(v[0]), "=&v"(v[1]), "=&v"(v[2]), "=&v"(v[3]),
        "=&v"(v[4]), "=&v"(v[5]), "=&v"(v[6]), "=&v"(v[7]),
        "=&s"(sacc)
      : "v"(a0), "v"(a0 + 2048), "v"(a0 + 4096), "v"(a0 + 6144),
        "s"(SENT64)
      : "vcc", "memory");
}

__device__ __forceinline__ void wg_barrier() {
  __builtin_amdgcn_sched_barrier(0);
  asm volatile("s_waitcnt lgkmcnt(0)" ::: "memory");
  __builtin_amdgcn_s_barrier();
  __builtin_amdgcn_sched_barrier(0);
}

// Row permutation: row' = p*256 + T*16 + u (T=0..15,u=0..15)
// gate g=u&3; j=(T>>2)*16+((u>>2)<<2)+(T&3); r_orig=g*256+p*64+j  [HW-verified R3]
__device__ __forceinline__ int rowp_to_orig(int rowp) {
  int p = rowp >> 8, T = (rowp >> 4) & 15, u = rowp & 15;
  int g = u & 3;
  int j = ((T >> 2) << 4) + ((u >> 2) << 2) + (T & 3);
  return g * 256 + p * 64 + j;
}

// ---------------- prep ----------------
#define PREP_TOTAL (16384 + 65536 + 1024 + 1024 + 524288 + 262144 + 32768)

__global__ void prep_kernel(const float* __restrict__ enc_w, const float* __restrict__ enc_b,
                            const float* __restrict__ w_ih, const float* __restrict__ w_hh,
                            const float* __restrict__ b_ih, const float* __restrict__ b_hh,
                            const float* __restrict__ dec_w,
                            u16* __restrict__ WDEC, u16* __restrict__ CW,
                            float* __restrict__ CB, float* __restrict__ B1P,
                            u16* __restrict__ WHHP, u16* __restrict__ WIH1P,
                            u16* __restrict__ HX0, u16* __restrict__ HX1)
{
  size_t idx = (size_t)blockIdx.x * 256 + threadIdx.x;
  if (idx < 16384) { WDEC[idx] = f2bf(dec_w[idx]); return; }
  idx -= 16384;
  if (idx < 65536) {
    int rowp = (int)(idx >> 6), f = (int)(idx & 63);
    int r = rowp_to_orig(rowp);
    float a = 0.f;
    for (int k = 0; k < 256; ++k) a += w_ih[r * 256 + k] * enc_w[k * 64 + f];
    CW[idx] = f2bf(a);
    return;
  }
  idx -= 65536;
  if (idx < 1024) {
    int r = rowp_to_orig((int)idx);
    float a = b_ih[r] + b_hh[r];
    for (int k = 0; k < 256; ++k) a += w_ih[r * 256 + k] * enc_b[k];
    CB[idx] = a;
    return;
  }
  idx -= 1024;
  if (idx < 1024) {
    int r = rowp_to_orig((int)idx);
    B1P[idx] = b_ih[1024 + r] + b_hh[1024 + r];
    return;
  }
  idx -= 1024;
  if (idx < 524288) {   // WHHP: flat = ((((l*4+p)*4+w)*4+t)*8+kc)*512 + lane*8 + e
    int l = (int)(idx >> 18);
    int rem = (int)(idx & 262143);
    int e = rem & 7, lane = (rem >> 3) & 63, kc = (rem >> 9) & 7;
    int t = (rem >> 12) & 3, wv = (rem >> 14) & 3, pp = (rem >> 16) & 3;
    int u = lane & 15, qd = lane >> 4;
    int g = u & 3;
    int j = wv * 16 + ((u >> 2) << 2) + t;
    int r = g * 256 + pp * 64 + j;
    int k = kc * 32 + qd * 8 + e;
    WHHP[idx] = f2bf(w_hh[(size_t)l * 262144 + (size_t)r * 256 + k]);
    return;
  }
  idx -= 524288;
  if (idx < 262144) {   // WIH1P (l=1)
    int rem = (int)idx;
    int e = rem & 7, lane = (rem >> 3) & 63, kc = (rem >> 9) & 7;
    int t = (rem >> 12) & 3, wv = (rem >> 14) & 3, pp = (rem >> 16) & 3;
    int u = lane & 15, qd = lane >> 4;
    int g = u & 3;
    int j = wv * 16 + ((u >> 2) << 2) + t;
    int r = g * 256 + pp * 64 + j;
    int k = kc * 32 + qd * 8 + e;
    WIH1P[idx] = f2bf(w_ih[262144 + (size_t)r * 256 + k]);
    return;
  }
  idx -= 262144;
  if (idx < 32768) {    // zero slot0 (overwrites the 0x7F memset)
    if (idx < 16384) HX0[idx] = 0;
    else             HX1[idx - 16384] = 0;
  }
}

// ---------------- generic bf16 GEMM:  C(MxN) = A(MxK) * B(NxK)^T + bias ----------------
template<int KTILES, int OUTBF, int BMODE, int AF32>
__global__ __launch_bounds__(256, 1) void gemm_bt(
    const void* __restrict__ Av, const u16* __restrict__ B, void* __restrict__ Cv,
    const float* __restrict__ bias, size_t ldc)
{
  constexpr int K = KTILES * 64;
  __shared__ __align__(16) u16 Asl[64 * 72];
  __shared__ __align__(16) u16 Bsl[64 * 72];
  const int tid = threadIdx.x;
  const int w = tid >> 6, lane = tid & 63, lm = lane & 15, quad = lane >> 4;
  const size_t m0 = (size_t)blockIdx.y * 64, n0 = (size_t)blockIdx.x * 64;

  f32x4 acc[4];
#pragma unroll
  for (int nt = 0; nt < 4; ++nt) { f32x4 z = {0.f, 0.f, 0.f, 0.f}; acc[nt] = z; }

  for (int kb = 0; kb < KTILES; ++kb) {
    if (AF32) {
      const float* Af = (const float*)Av;
#pragma unroll
      for (int c = 0; c < 4; ++c) {
        int idx = c * 256 + tid;
        int row = idx >> 4, k4 = idx & 15;
        float4 v = *(const float4*)(Af + (m0 + row) * (size_t)K + kb * 64 + k4 * 4);
        u64 pv = (u64)f2bf(v.x) | ((u64)f2bf(v.y) << 16) |
                 ((u64)f2bf(v.z) << 32) | ((u64)f2bf(v.w) << 48);
        *(u64*)(&Asl[row * 72 + k4 * 4]) = pv;
      }
    } else {
      const u16* Ab = (const u16*)Av;
#pragma unroll
      for (int c = 0; c < 2; ++c) {
        int idx = c * 256 + tid;
        int row = idx >> 3, k8 = idx & 7;
        *(uint4*)(&Asl[row * 72 + k8 * 8]) =
            *(const uint4*)(Ab + (m0 + row) * (size_t)K + kb * 64 + k8 * 8);
      }
    }
#pragma unroll
    for (int c = 0; c < 2; ++c) {
      int idx = c * 256 + tid;
      int row = idx >> 3, k8 = idx & 7;
      *(uint4*)(&Bsl[row * 72 + k8 * 8]) =
          *(const uint4*)(B + (n0 + row) * (size_t)K + kb * 64 + k8 * 8);
    }
    __syncthreads();
#pragma unroll
    for (int kc = 0; kc < 2; ++kc) {
      short8 a = *(const short8*)(&Asl[(w * 16 + lm) * 72 + kc * 32 + quad * 8]);
#pragma unroll
      for (int nt = 0; nt < 4; ++nt) {
        short8 b = *(const short8*)(&Bsl[(nt * 16 + lm) * 72 + kc * 32 + quad * 8]);
        acc[nt] = __builtin_amdgcn_mfma_f32_16x16x32_bf16(a, b, acc[nt], 0, 0, 0);
      }
    }
    __syncthreads();
  }
#pragma unroll
  for (int nt = 0; nt < 4; ++nt) {
    size_t n = n0 + nt * 16 + lm;
    float bn = (BMODE == 1) ? bias[n] : 0.f;
#pragma unroll
    for (int r = 0; r < 4; ++r) {
      size_t m = m0 + w * 16 + quad * 4 + r;
      float v = acc[nt][r] + ((BMODE == 2) ? bias[m] : bn);
      if (OUTBF) ((u16*)Cv)[m * ldc + n] = f2bf(v);
      else       ((float*)Cv)[m * ldc + n] = v;
    }
  }
}

// ---------------- sentinel-poll gather: one 32 b x 256 j h-slab -> LDS ----------------
// Thread owns column j4 = tid&63 across 8 row-quads. Pipelined in-asm poll.
__device__ __forceinline__ void gather32(const u16* __restrict__ src,
                                         u16* __restrict__ dst,
                                         int tid, int n2, bool skip, int p)
{
  const int j4 = tid & 63;
  const int tw = tid >> 6;
  if (skip && ((j4 >> 4) == p)) return;
  const u16* a0 = src + ((size_t)(n2 * 32 + tw) * 256 + j4 * 4);
  u64 v[8];
  poll8(a0, v);
#pragma unroll
  for (int i = 0; i < 8; ++i)
    *(u64*)(dst + (i * 4 + tw) * 264 + j4 * 4) = v[i];
}

// ---------------- fused 2-layer dataflow recurrence (16 wgs, agent scope) ----------------
// role = blockIdx.x: layer = role>>3, p = role&3, n2 = (role>>2)&1.
// hx layout: [slot 0..CS][64 b][256 j] u16; slot s holds h(base+s); slot0 = h(base).
__global__ __launch_bounds__(256, 1) void lstm_fused(
    const u16* __restrict__ xg0, u16* __restrict__ x2,
    const u16* __restrict__ whhp, const u16* __restrict__ wih1p,
    const float* __restrict__ b1p,
    u16* __restrict__ hx0, u16* __restrict__ hx1,
    float* __restrict__ cstb, int base)
{
  __shared__ __align__(16) u16 Hl[2][2][32 * 264];   // [parity][buf] +8 u16 row pad
  const int tid = threadIdx.x;
  const int role = blockIdx.x;
  const int layer = role >> 3, p = role & 3, n2 = (role >> 2) & 1;
  const int lane = tid & 63, w = tid >> 6, lm = lane & 15, quad = lane >> 4;
  const int j4 = tid & 63, tw = tid >> 6;

  // ---- weights into VGPR fragments ----
  short8 wfh[4][8], wfi[4][8];
  {
    const u16* wp = whhp + (size_t)((layer * 4 + p) * 4 + w) * 16384 + lane * 8;
#pragma unroll
    for (int t = 0; t < 4; ++t)
#pragma unroll
      for (int kc = 0; kc < 8; ++kc)
        wfh[t][kc] = *(const short8*)(wp + (t * 8 + kc) * 512);
  }
  f32x4 bias_f[4];
  if (layer) {
    const u16* wp = wih1p + (size_t)(p * 4 + w) * 16384 + lane * 8;
#pragma unroll
    for (int t = 0; t < 4; ++t)
#pragma unroll
      for (int kc = 0; kc < 8; ++kc)
        wfi[t][kc] = *(const short8*)(wp + (t * 8 + kc) * 512);
#pragma unroll
    for (int t = 0; t < 4; ++t)
      bias_f[t] = *(const f32x4*)(b1p + p * 256 + (w * 4 + t) * 16 + quad * 4);
  }

  float* cp = cstb + (size_t)(((layer * 4 + p) * 2 + n2) * 256 + tid) * 8;
  float cst[4][2];
  if (base) {
#pragma unroll
    for (int t = 0; t < 4; ++t) { cst[t][0] = cp[t * 2]; cst[t][1] = cp[t * 2 + 1]; }
  } else {
#pragma unroll
    for (int t = 0; t < 4; ++t) { cst[t][0] = 0.f; cst[t][1] = 0.f; }
  }

  const int jcol = p * 64 + w * 16 + quad * 4;
  u16* myhx = layer ? hx1 : hx0;
  u64 hprev[2] = {0, 0};

  for (int s = 1; s <= CS; ++s) {
    const int cur = s & 1;
    const bool own = (s > 1);          // own slice comes from hprev regs
    f32x4 acc[4][2];

    if (layer == 0) {
      // xg loads early to overlap with the poll
      u64 xv[4][2];
#pragma unroll
      for (int t = 0; t < 4; ++t)
#pragma unroll
        for (int nt = 0; nt < 2; ++nt)
          xv[t][nt] = *(const u64*)(xg0 +
              ((size_t)(s - 1) * 64 + n2 * 32 + nt * 16 + lm) * 1024 +
              p * 256 + (w * 4 + t) * 16 + quad * 4);
      gather32(hx0 + (size_t)(s - 1) * SLOT, &Hl[cur][0][0], tid, n2, own, p);
      if (own) {
#pragma unroll
        for (int nt = 0; nt < 2; ++nt)
          *(u64*)(&Hl[cur][0][(nt * 16 + lm) * 264 + jcol]) = hprev[nt];
      }
      wg_barrier();
#pragma unroll
      for (int t = 0; t < 4; ++t)
#pragma unroll
        for (int nt = 0; nt < 2; ++nt) {
          u64 v = xv[t][nt];
          f32x4 tt = { bf2f((u16)v), bf2f((u16)(v >> 16)),
                       bf2f((u16)(v >> 32)), bf2f((u16)(v >> 48)) };
          acc[t][nt] = tt;
        }
#pragma unroll
      for (int kc = 0; kc < 8; ++kc) {
        short8 b0[2];
#pragma unroll
        for (int nt = 0; nt < 2; ++nt)
          b0[nt] = *(const short8*)(&Hl[cur][0][(nt * 16 + lm) * 264 + kc * 32 + quad * 8]);
#pragma unroll
        for (int t = 0; t < 4; ++t)
#pragma unroll
          for (int nt = 0; nt < 2; ++nt)
            acc[t][nt] = __builtin_amdgcn_mfma_f32_16x16x32_bf16(
                wfh[t][kc], b0[nt], acc[t][nt], 0, 0, 0);
      }
    } else {
      // (a) stale h1(s-1) gather — published a full step ago, usually instant
      gather32(hx1 + (size_t)(s - 1) * SLOT, &Hl[cur][1][0], tid, n2, own, p);
      if (own) {
#pragma unroll
        for (int nt = 0; nt < 2; ++nt)
          *(u64*)(&Hl[cur][1][(nt * 16 + lm) * 264 + jcol]) = hprev[nt];
      }
      // (b) issue fresh h0(s) first-round loads NOW; they fly under the
      //     barrier + W_hh chain (R8-proven deferred-issue profile)
      const u16* ah = hx0 + (size_t)s * SLOT +
                      ((size_t)(n2 * 32 + tw) * 256 + j4 * 4);
      u64 vh[8];
      ld8_issue(ah, vh);
      wg_barrier();
      // (c) acc = bias; W_hh x h1(s-1) chain (does not need h0)
#pragma unroll
      for (int t = 0; t < 4; ++t)
#pragma unroll
        for (int nt = 0; nt < 2; ++nt) acc[t][nt] = bias_f[t];
#pragma unroll
      for (int kc = 0; kc < 8; ++kc) {
        short8 b1[2];
#pragma unroll
        for (int nt = 0; nt < 2; ++nt)
          b1[nt] = *(const short8*)(&Hl[cur][1][(nt * 16 + lm) * 264 + kc * 32 + quad * 8]);
#pragma unroll
        for (int t = 0; t < 4; ++t)
#pragma unroll
          for (int nt = 0; nt < 2; ++nt)
            acc[t][nt] = __builtin_amdgcn_mfma_f32_16x16x32_bf16(
                wfh[t][kc], b1[nt], acc[t][nt], 0, 0, 0);
      }
      // (d) wait on the in-flight h0 loads; if late, pipelined in-asm poll
      vmwait8(vh);
      {
        bool bad = false;
#pragma unroll
        for (int i = 0; i < 8; ++i) bad |= (vh[i] == SENT64);
        if (bad) poll8(ah, vh);
      }
#pragma unroll
      for (int i = 0; i < 8; ++i)
        *(u64*)(&Hl[cur][0][(i * 4 + tw) * 264 + j4 * 4]) = vh[i];
      wg_barrier();
      // (e) W_ih x h0(s) chain
#pragma unroll
      for (int kc = 0; kc < 8; ++kc) {
        short8 b0[2];
#pragma unroll
        for (int nt = 0; nt < 2; ++nt)
          b0[nt] = *(const short8*)(&Hl[cur][0][(nt * 16 + lm) * 264 + kc * 32 + quad * 8]);
#pragma unroll
        for (int t = 0; t < 4; ++t)
#pragma unroll
          for (int nt = 0; nt < 2; ++nt)
            acc[t][nt] = __builtin_amdgcn_mfma_f32_16x16x32_bf16(
                wfi[t][kc], b0[nt], acc[t][nt], 0, 0, 0);
      }
    }

    // ---- nonlinearity + fire-and-forget publish (no drain, no flag) ----
    u16* hd = myhx + (size_t)s * SLOT;
#pragma unroll
    for (int nt = 0; nt < 2; ++nt) {
      u64 h = 0;
#pragma unroll
      for (int t = 0; t < 4; ++t) {
        float iv = sigf(acc[t][nt][0]);
        float fv = sigf(acc[t][nt][1]);
        float gv = tanhf_fast(acc[t][nt][2]);
        float ov = sigf(acc[t][nt][3]);
        float cv = fv * cst[t][nt] + iv * gv;
        cst[t][nt] = cv;
        h |= (u64)f2bf(ov * tanhf_fast(cv)) << (16 * t);
      }
      const int b = n2 * 32 + nt * 16 + lm;
      astore(hd + (size_t)b * 256 + jcol, h);
      if (s == CS) astore(myhx + (size_t)b * 256 + jcol, h);   // seed next chunk
      if (layer) *(u64*)(x2 + ((size_t)(s - 1) * 64 + b) * 256 + jcol) = h;
      hprev[nt] = h;
    }
    // no end-of-step barrier: next step writes the other LDS parity.
  }
#pragma unroll
  for (int t = 0; t < 4; ++t) { cp[t * 2] = cst[t][0]; cp[t * 2 + 1] = cst[t][1]; }
}

// ---------------- launch ----------------
extern "C" void kernel_launch(void* const* d_in, const int* in_sizes, int n_in,
                              void* d_out, int out_size, void* d_ws, size_t ws_size,
                              hipStream_t stream)
{
  const float* in0   = (const float*)d_in[0];
  const float* enc_w = (const float*)d_in[1];
  const float* enc_b = (const float*)d_in[2];
  const float* w_ih  = (const float*)d_in[3];
  const float* w_hh  = (const float*)d_in[4];
  const float* b_ih  = (const float*)d_in[5];
  const float* b_hh  = (const float*)d_in[6];
  const float* dec_w = (const float*)d_in[7];
  const float* dec_b = (const float*)d_in[8];

  char* ws = (char*)d_ws;
  u16*   XG    = (u16*)(ws);                 // 16,777,216  xg0 chunk [CN][1024]
  u16*   X2    = (u16*)(ws + 16777216);      //  4,194,304  x2 chunk [CN][256]
  u16*   WHHP  = (u16*)(ws + 20971520);      //  1,048,576
  u16*   WIH1P = (u16*)(ws + 22020096);      //    524,288
  u16*   CW    = (u16*)(ws + 22544384);      //    131,072
  u16*   WDEC  = (u16*)(ws + 22675456);      //     32,768
  float* CB    = (float*)(ws + 22708224);    //      4,096
  float* B1P   = (float*)(ws + 22712320);    //      4,096
  u16*   HX0   = (u16*)(ws + 22716416);      //  4,227,072  [CS+1 slots][64][256]
  u16*   HX1   = (u16*)(ws + 26943488);      //  4,227,072
  float* CST   = (float*)(ws + 31170560);    //    131,072

  if (ws_size < 31301632) return;   // diagnostic guard

  // sentinel-fill both h histories, then prep zeroes slot0 (h(0)=0)
  hipMemsetAsync(HX0, 0x7F, HXBYTES, stream);
  hipMemsetAsync(HX1, 0x7F, HXBYTES, stream);

  prep_kernel<<<dim3((PREP_TOTAL + 255) / 256), 256, 0, stream>>>(
      enc_w, enc_b, w_ih, w_hh, b_ih, b_hh, dec_w,
      WDEC, CW, CB, B1P, WHHP, WIH1P, HX0, HX1);

  for (int c = 0; c < NCH; ++c) {
    const float* inc = in0 + (size_t)c * CN * 64;
    float* outc = (float*)d_out + (size_t)c * CN * 64;
    // xg0 = inc @ CW^T + CB  (encoder folded in; M=CN, N=1024, K=64)
    gemm_bt<1, 1, 1, 1><<<dim3(16, CN / 64), 256, 0, stream>>>(inc, CW, XG, CB, 1024);
    // fused 2-layer dataflow recurrence
    lstm_fused<<<dim3(16), 256, 0, stream>>>(XG, X2, WHHP, WIH1P, B1P,
                                             HX0, HX1, CST, c * CS);
    // re-sentinel slots 1..CS for the next chunk (slot0 = fresh seed, keep)
    if (c + 1 < NCH) {
      hipMemsetAsync((char*)HX0 + SLOT * 2, 0x7F, HXBYTES - SLOT * 2, stream);
      hipMemsetAsync((char*)HX1 + SLOT * 2, 0x7F, HXBYTES - SLOT * 2, stream);
    }
    // decoder: outc = x2 @ dec_w^T + dec_b  (M=CN, N=64, K=256), fp32 out
    gemm_bt<4, 0, 1, 0><<<dim3(1, CN / 64), 256, 0, stream>>>(X2, WDEC, (void*)outc, dec_b, 64);
  }

  (void)in_sizes; (void)n_in; (void)out_size;
}